// Round 11
// baseline (143.317 us; speedup 1.0000x reference)
//
#include <hip/hip_runtime.h>
#include <hip/hip_bf16.h>

// RoI crop: out[n,b,i,j,c] = features[b, x1(n)+i, y1(n)+j, c]
// features: [B=8, 64, 64, C=256] f32 ; boxes: [N=1000, 4] i32 (x1,y1,x2,y2)
// out: [N, B, 7, 7, C] f32  (401 MB streaming write)
//
// R10: x1-sorted processing order + PLAIN stores.
// Established: nt-store path caps ~5.2 TB/s (R3/R5/R7/R9); plain stores
// reach 6.9 TB/s (fill) but evicted the 4MB-per-XCD read slice when boxes
// arrive in random x1 order (R4: 95us). Fix the CAUSE: a tiny rank-sort
// kernel orders boxes by x1; blocks within an XCD then read a ~1MB
// SLIDING row window (resident blocks span ~8 x1 values + 7-row extent),
// leaving ~3MB of L2 for the plain-store write-back stream at fill rate.
//  - sort kernel: deterministic rank = #{x1<mine} + #{x1==mine, idx<mine};
//    collision-free scatter, no atomics, ~3us on 8 CUs.
//  - main kernel: R9 structure (XCD pin b=blockIdx&7, fire-and-forget,
//    half-planes, buf[<=7]) with n = perm[u>>1] and plain stores.

#define ANCHOR 7
#define FS     64
#define NBOX   1000
#define BB     8
#define CC     256
#define C4     (CC / 4)                 // 64 f32x4 per 1KB row
#define ROWS   (BB * ANCHOR * ANCHOR)   // 392 rows per box
#define MAXR   7

typedef float f32x4 __attribute__((ext_vector_type(4)));

__global__ __launch_bounds__(128) void box_rank_sort_kernel(
    const int* __restrict__ boxes,      // [N,4]
    int*       __restrict__ perm)       // [N] out: perm[rank] = box index
{
    __shared__ int xs[NBOX];
    const int tid = threadIdx.x;        // 0..127
    for (int s = tid; s < NBOX; s += 128)
        xs[s] = min(max(boxes[4 * s], 0), FS - ANCHOR);
    __syncthreads();

    const int idx = blockIdx.x * 125 + tid;   // 8 blocks x 125 boxes
    if (tid < 125) {
        const int myx = xs[idx];
        int pos = 0;
        for (int s = 0; s < NBOX; ++s) {
            const int v = xs[s];
            pos += (v < myx) | ((v == myx) & (s < idx));
        }
        perm[pos] = idx;                      // deterministic, collision-free
    }
}

__global__ __launch_bounds__(256) void roi_crop_kernel(
    const f32x4* __restrict__ fin,      // features as f32x4
    const int*   __restrict__ boxes,    // [N,4]
    const int*   __restrict__ perm,     // [N] x1-sorted box order
    f32x4*       __restrict__ fout)     // out as f32x4
{
    const int lane = threadIdx.x & 63;
    const int wave = threadIdx.x >> 6;          // 0..3
    const int x    = blockIdx.x;                // 0..15999
    const int b    = x & 7;                     // batch slice == XCD id
    const int u    = x >> 3;                    // 0..1999, monotone per XCD
    const int n    = perm[u >> 1];              // box index, x1-sorted order
    const int half = u & 1;                     // which half of the 49 rows

    int x1 = boxes[n * 4 + 0];
    int y1 = boxes[n * 4 + 1];
    x1 = min(max(x1, 0), FS - ANCHOR);
    y1 = min(max(y1, 0), FS - ANCHOR);

    // half 0: rows [0,25) as [7,6,6,6]; half 1: rows [25,49) as [6,6,6,6]
    const int start = half ? (25 + 6 * wave)
                           : (wave ? 1 + 6 * wave : 0);
    const int cnt   = (!half && wave == 0) ? 7 : 6;

    const f32x4* __restrict__ src = fin + ((b * FS + x1) * FS + y1) * C4 + lane;
    f32x4* __restrict__ dst = fout + n * (ROWS * C4) + b * (ANCHOR * ANCHOR * C4)
                              + start * C4 + lane;

    f32x4 buf[MAXR];

    // phase 1: issue ALL loads (vmcnt queue = loads only)
    #pragma unroll
    for (int t = 0; t < MAXR; ++t) {
        if (t < cnt) {                       // wave-uniform branch
            int r = start + t;
            int i = r / ANCHOR;
            int j = r - i * ANCHOR;
            buf[t] = src[(i * FS + j) * C4];
        }
    }

    // phase 2: PLAIN stores -> L2 write-back path (fill-proven 6.9 TB/s);
    // wave retires with stores in flight.
    #pragma unroll
    for (int t = 0; t < MAXR; ++t) {
        if (t < cnt)
            dst[t * C4] = buf[t];
    }
}

extern "C" void kernel_launch(void* const* d_in, const int* in_sizes, int n_in,
                              void* d_out, int out_size, void* d_ws, size_t ws_size,
                              hipStream_t stream) {
    const f32x4* fin  = (const f32x4*)d_in[0];
    const int*  boxes = (const int*)d_in[1];
    f32x4*      fout  = (f32x4*)d_out;
    int*        perm  = (int*)d_ws;           // 1000 ints = 4 KB scratch

    box_rank_sort_kernel<<<8, 128, 0, stream>>>(boxes, perm);
    roi_crop_kernel<<<NBOX * BB * 2, 256, 0, stream>>>(fin, boxes, perm, fout);
}

// Round 12
// 76.960 us; speedup vs baseline: 1.8622x; 1.8622x over previous
//
#include <hip/hip_runtime.h>
#include <hip/hip_bf16.h>

// RoI crop: out[n,b,i,j,c] = features[b, x1(n)+i, y1(n)+j, c]
// features: [B=8, 64, 64, C=256] f32 ; boxes: [N=1000, 4] i32 (x1,y1,x2,y2)
// out: [N, B, 7, 7, C] f32  (401 MB streaming write)
//
// FINAL (= R9, best at 76.55us, ~5.7 TB/s effective = 90% of the 6.29 TB/s
// achievable mixed-stream BW). Design settled by the R0-R10 ladder:
//  - XCD-pinned reads: b = blockIdx&7 -> each XCD's L2 holds exactly its
//    4 MB feature slice; reads are L2 hits. (R6: reads via L3 = 152us.)
//  - NT stores: the write stream must bypass L2 or it evicts the pinned
//    read slice (R4: 95us, R8: 85us, R10 sorted+plain: 143us). The nt
//    path caps ~5.2 TB/s (R3/R5/R7/R9 all converge there) — that cap,
//    not scheduling, is the binding constraint.
//  - Fire-and-forget waves: all loads -> one vmcnt (loads only) -> all
//    nt stores -> s_endpgm with stores in flight; no load ever queues
//    behind a store in the vmcnt FIFO (R7: -4%).
//  - Half-plane blocks: buf[<=7] keeps ~45 VGPR -> 8 waves/SIMD (R9: -2%).

#define ANCHOR 7
#define FS     64
#define NBOX   1000
#define BB     8
#define CC     256
#define C4     (CC / 4)                 // 64 f32x4 per 1KB row
#define ROWS   (BB * ANCHOR * ANCHOR)   // 392 rows per box
#define MAXR   7

typedef float f32x4 __attribute__((ext_vector_type(4)));

__global__ __launch_bounds__(256) void roi_crop_kernel(
    const f32x4* __restrict__ fin,      // features as f32x4
    const int*   __restrict__ boxes,    // [N,4]
    f32x4*       __restrict__ fout)     // out as f32x4
{
    const int lane = threadIdx.x & 63;
    const int wave = threadIdx.x >> 6;          // 0..3
    const int x    = blockIdx.x;                // 0..15999
    const int b    = x & 7;                     // batch slice == XCD id
    const int u    = x >> 3;                    // 0..1999
    const int n    = u >> 1;                    // box index, 0..999
    const int half = u & 1;                     // which half of the 49 rows

    int x1 = boxes[n * 4 + 0];
    int y1 = boxes[n * 4 + 1];
    x1 = min(max(x1, 0), FS - ANCHOR);
    y1 = min(max(y1, 0), FS - ANCHOR);

    // half 0: rows [0,25) as [7,6,6,6]; half 1: rows [25,49) as [6,6,6,6]
    const int start = half ? (25 + 6 * wave)
                           : (wave ? 1 + 6 * wave : 0);
    const int cnt   = (!half && wave == 0) ? 7 : 6;

    const f32x4* __restrict__ src = fin + ((b * FS + x1) * FS + y1) * C4 + lane;
    f32x4* __restrict__ dst = fout + n * (ROWS * C4) + b * (ANCHOR * ANCHOR * C4)
                              + start * C4 + lane;

    f32x4 buf[MAXR];

    // phase 1: issue ALL loads (vmcnt queue = loads only)
    #pragma unroll
    for (int t = 0; t < MAXR; ++t) {
        if (t < cnt) {                       // wave-uniform branch
            int r = start + t;
            int i = r / ANCHOR;
            int j = r - i * ANCHOR;
            buf[t] = src[(i * FS + j) * C4];
        }
    }

    // phase 2: all nt stores; wave retires with stores in flight.
    #pragma unroll
    for (int t = 0; t < MAXR; ++t) {
        if (t < cnt)
            __builtin_nontemporal_store(buf[t], &dst[t * C4]);
    }
}

extern "C" void kernel_launch(void* const* d_in, const int* in_sizes, int n_in,
                              void* d_out, int out_size, void* d_ws, size_t ws_size,
                              hipStream_t stream) {
    const f32x4* fin  = (const f32x4*)d_in[0];
    const int*  boxes = (const int*)d_in[1];
    f32x4*      fout  = (f32x4*)d_out;

    roi_crop_kernel<<<NBOX * BB * 2, 256, 0, stream>>>(fin, boxes, fout);
}